// Round 1
// 992.208 us; speedup vs baseline: 1.0990x; 1.0990x over previous
//
#include <hip/hip_runtime.h>
#include <math.h>

// Problem constants: B=1024, E=64, N=32, D=64
#define NB  1024
#define NE  64
#define NN  32
#define ND  64
#define PPB 16   // pairs per block (16 | 64, so all pairs in a block share b)

// Persistent block over PPB consecutive (b,e) pairs.
// Per pair, thread t owns float4-chunk t and t+256 of each 32x64 tile:
//   chunk k -> row n = k>>4, float4-col c = k&15.
// W (32KB) lives in registers: thread t holds W4[t*8 .. t*8+7]
//   == rows dout=t>>2, quarter q=t&3 (the GEMV layout), loaded coalesced once.
__global__ __launch_bounds__(256) void kgcn_agg_kernel(
    const float* __restrict__ self_v,   // [B,E,1,D]
    const float* __restrict__ nbr_v,    // [B,E,N,D]
    const float* __restrict__ nbr_r,    // [B,E,N,D]
    const float* __restrict__ user,     // [B,D]
    const float* __restrict__ W,        // [D, 2D] row-major
    const float* __restrict__ bias,     // [D]
    float* __restrict__ out)            // [B,E,D]
{
    const int t     = threadIdx.x;        // 0..255
    const int pair0 = blockIdx.x * PPB;
    const int b     = pair0 >> 6;         // constant over the block's pairs

    const int col  = t & 15;   // float4 column 0..15
    const int rg   = t >> 4;   // row-group 0..15 (rows rg and rg+16)
    const int lane = t & 63;
    const int wv   = t >> 6;   // wave 0..3

    // double-buffered LDS; x chunk c stored at index c + (c>>3) (pad kills
    // the 4-way bank conflict of the old q*8+i read pattern)
    __shared__ float  s_scores[2][NN];
    __shared__ float4 s_part4[2][64];
    __shared__ float4 s_x4[2][36];

    // ---- per-block invariants: user vec, bias, W -> registers ----
    const float4 u4v = ((const float4*)(user + (size_t)b * ND))[col];
    const float  bv  = bias[t >> 2];
    float4 wr[8];
    {
        const float4* W4 = (const float4*)W;
        #pragma unroll
        for (int i = 0; i < 8; ++i)
            wr[i] = W4[t * 8 + i];   // coalesced: lane-contiguous 32KB preload
    }

    const float4* rel4 = (const float4*)(nbr_r + (size_t)pair0 * (NN * ND));
    const float4* nv4  = (const float4*)(nbr_v + (size_t)pair0 * (NN * ND));
    const float4* sv4  = (const float4*)(self_v + (size_t)pair0 * ND);
    float* outp = out + (size_t)pair0 * ND;

    #pragma unroll 1
    for (int it = 0; it < PPB; ++it) {
        const int buf  = it & 1;
        const int base = it * 512;   // 512 float4 per 32x64 tile

        // ---- issue all streaming loads up front ----
        float4 ra = rel4[base + t];
        float4 rb = rel4[base + t + 256];
        float4 va = nv4[base + t];
        float4 vb = nv4[base + t + 256];
        float4 sv;
        if (t < 16) sv = sv4[it * 16 + t];

        // ---- scores = user . rel, 16-lane butterfly per row ----
        float pa = ra.x*u4v.x + ra.y*u4v.y + ra.z*u4v.z + ra.w*u4v.w;
        float pb = rb.x*u4v.x + rb.y*u4v.y + rb.z*u4v.z + rb.w*u4v.w;
        #pragma unroll
        for (int off = 8; off > 0; off >>= 1) {
            pa += __shfl_xor(pa, off, 16);
            pb += __shfl_xor(pb, off, 16);
        }
        if (col == 0) {
            s_scores[buf][rg]      = pa;
            s_scores[buf][rg + 16] = pb;
        }
        if (t < 16) {
            int c = t;                           // self -> x chunks 0..15
            s_x4[buf][c + (c >> 3)] = sv;
        }
        __syncthreads();   // B1: scores + self visible

        // ---- wave-parallel softmax (redundant per 32-lane half) ----
        float v = s_scores[buf][t & 31];         // same-address broadcast, free
        float m = v;
        #pragma unroll
        for (int off = 16; off > 0; off >>= 1)
            m = fmaxf(m, __shfl_xor(m, off, 32));
        float e = __expf(v - m);
        float ssum = e;
        #pragma unroll
        for (int off = 16; off > 0; off >>= 1)
            ssum += __shfl_xor(ssum, off, 32);
        float rs  = __builtin_amdgcn_rcpf(ssum);
        float p_a = __shfl(e, rg, 32) * rs;      // p for row rg
        float p_b = __shfl(e, rg + 16, 32) * rs; // p for row rg+16

        // ---- agg partial: this thread's 2 rows ----
        float4 acc;
        acc.x = p_a * va.x + p_b * vb.x;
        acc.y = p_a * va.y + p_b * vb.y;
        acc.z = p_a * va.z + p_b * vb.z;
        acc.w = p_a * va.w + p_b * vb.w;
        // reduce the 4 row-groups inside this wave (lanes l, l^16, l^32 share col)
        acc.x += __shfl_xor(acc.x, 16, 64);
        acc.y += __shfl_xor(acc.y, 16, 64);
        acc.z += __shfl_xor(acc.z, 16, 64);
        acc.w += __shfl_xor(acc.w, 16, 64);
        acc.x += __shfl_xor(acc.x, 32, 64);
        acc.y += __shfl_xor(acc.y, 32, 64);
        acc.z += __shfl_xor(acc.z, 32, 64);
        acc.w += __shfl_xor(acc.w, 32, 64);
        if (lane < 16) s_part4[buf][wv * 16 + lane] = acc;  // one partial per wave
        __syncthreads();   // B2: wave partials visible

        // ---- final 4-way reduce -> x agg half ----
        if (t < 16) {
            float4 a0 = s_part4[buf][t];
            float4 a1 = s_part4[buf][16 + t];
            float4 a2 = s_part4[buf][32 + t];
            float4 a3 = s_part4[buf][48 + t];
            float4 s;
            s.x = (a0.x + a1.x) + (a2.x + a3.x);
            s.y = (a0.y + a1.y) + (a2.y + a3.y);
            s.z = (a0.z + a1.z) + (a2.z + a3.z);
            s.w = (a0.w + a1.w) + (a2.w + a3.w);
            int c = 16 + t;                      // agg -> x chunks 16..31
            s_x4[buf][c + (c >> 3)] = s;
        }
        __syncthreads();   // B3: x ready

        // ---- GEMV from registers: out = relu(x @ W^T + b) ----
        const int q = t & 3;
        float acc2 = 0.f;
        #pragma unroll
        for (int i = 0; i < 8; ++i) {
            float4 x = s_x4[buf][q * 9 + i];     // == padded index of chunk q*8+i
            acc2 += wr[i].x * x.x + wr[i].y * x.y + wr[i].z * x.z + wr[i].w * x.w;
        }
        acc2 += __shfl_down(acc2, 2, 4);
        acc2 += __shfl_down(acc2, 1, 4);
        if (q == 0) {
            float r = acc2 + bv;
            outp[it * ND + (t >> 2)] = fmaxf(r, 0.f);
        }
    }
}

extern "C" void kernel_launch(void* const* d_in, const int* in_sizes, int n_in,
                              void* d_out, int out_size, void* d_ws, size_t ws_size,
                              hipStream_t stream) {
    const float* self_v = (const float*)d_in[0];
    const float* nbr_v  = (const float*)d_in[1];
    const float* nbr_r  = (const float*)d_in[2];
    const float* user   = (const float*)d_in[3];
    const float* W      = (const float*)d_in[4];
    const float* bias   = (const float*)d_in[5];
    float* out          = (float*)d_out;

    const int n_blocks = (NB * NE) / PPB;  // 4096 persistent-ish blocks
    kgcn_agg_kernel<<<n_blocks, 256, 0, stream>>>(
        self_v, nbr_v, nbr_r, user, W, bias, out);
}